// Round 13
// baseline (196.932 us; speedup 1.0000x reference)
//
#include <hip/hip_runtime.h>

// Problem constants (from reference)
#define B_    32
#define C_    256
#define HW    3136               // 56*56
#define HW4   784                // f32x4 per channel plane (= 3*256 + 16)
#define NSEL  8
#define NTOT  (B_ * C_ * HW)     // 25,690,112 elements
#define NTOT4 (NTOT / 4)         // 6,422,528 f32x4
#define NSELTOT4 (B_ * NSEL * HW4)  // 200,704 f32x4 in selected slice
#define PLANES (B_ * C_)         // 8192 (b,c) planes

#define RB  64                   // reduction blocks (one wave of partials)
#define TPB 256

typedef float f32x4 __attribute__((ext_vector_type(4)));

// ws layout (floats): [0..64) partial mins | [64..128) partial maxes
__global__ __launch_bounds__(TPB)
void k_minmax(const float* __restrict__ in, const int* __restrict__ sel,
              float* __restrict__ ws) {
    __shared__ float smn[TPB], smx[TPB];
    __shared__ int ssel[NSEL];
    if (threadIdx.x < NSEL) ssel[threadIdx.x] = sel[threadIdx.x];
    __syncthreads();

    float mn = INFINITY, mx = -INFINITY;
    const f32x4* in4 = reinterpret_cast<const f32x4*>(in);
    for (int i = blockIdx.x * TPB + threadIdx.x; i < NSELTOT4;
         i += RB * TPB) {
        int pos = i % HW4;
        int t   = i / HW4;
        int j   = t % NSEL;
        int b   = t / NSEL;
        f32x4 v = in4[(b * C_ + ssel[j]) * HW4 + pos];
        mn = fminf(mn, fminf(fminf(v.x, v.y), fminf(v.z, v.w)));
        mx = fmaxf(mx, fmaxf(fmaxf(v.x, v.y), fmaxf(v.z, v.w)));
    }
    smn[threadIdx.x] = mn;
    smx[threadIdx.x] = mx;
    __syncthreads();
    for (int s = TPB / 2; s > 0; s >>= 1) {
        if (threadIdx.x < s) {
            smn[threadIdx.x] = fminf(smn[threadIdx.x], smn[threadIdx.x + s]);
            smx[threadIdx.x] = fmaxf(smx[threadIdx.x], smx[threadIdx.x + s]);
        }
        __syncthreads();
    }
    if (threadIdx.x == 0) {
        ws[blockIdx.x]      = smn[0];
        ws[RB + blockIdx.x] = smx[0];
    }
}

__device__ __forceinline__ float qmix(float x, float mn,
                                      float sc2, float sc4, float sc8,
                                      float sw0, float sw1, float sw2) {
    float d = x - mn;
    // jnp.round == round-half-to-even == rintf (default rounding mode)
    float q2 = fminf(fmaxf(rintf(d / sc2), 0.0f), 3.0f);
    float q4 = fminf(fmaxf(rintf(d / sc4), 0.0f), 15.0f);
    float q8 = fminf(fmaxf(rintf(d / sc8), 0.0f), 255.0f);
    float o2 = q2 * sc2 + mn;
    float o4 = q4 * sc4 + mn;
    float o8 = q8 * sc8 + mn;
    return o2 * sw0 + o4 * sw1 + o8 * sw2;  // same left-to-right order as ref
}

__device__ __forceinline__ void qmix4(f32x4& v, float mn,
                                      float sc2, float sc4, float sc8,
                                      float sw0, float sw1, float sw2) {
    v.x = qmix(v.x, mn, sc2, sc4, sc8, sw0, sw1, sw2);
    v.y = qmix(v.y, mn, sc2, sc4, sc8, sw0, sw1, sw2);
    v.z = qmix(v.z, mn, sc2, sc4, sc8, sw0, sw1, sw2);
    v.w = qmix(v.w, mn, sc2, sc4, sc8, sw0, sw1, sw2);
}

// Plane-major redesign vs round 11:
//  - one block per (b,c) plane -> channel id is blockIdx-derived (no
//    per-element div), copy-vs-quant branch is BLOCK-UNIFORM scalar
//  - each thread batches 4 independent loads then 4 stores (MLP=4; the
//    round-11 loop had 1 load in flight + vmcnt(0) store-serialization)
//  - finish = 64-partial wave-shuffle reduce, 1 barrier (was 8-barrier tree)
__global__ __launch_bounds__(TPB)
void k_main3(const float* __restrict__ in, const float* __restrict__ beta,
             const int* __restrict__ sel, float* __restrict__ out,
             const float* __restrict__ ws) {
    __shared__ float cns[8];  // mnf, sc2, sc4, sc8, sw0, sw1, sw2
    const int tid = threadIdx.x;

    if (tid < 64) {
        float pm = ws[tid];
        float px = ws[RB + tid];
        #pragma unroll
        for (int o = 32; o > 0; o >>= 1) {
            pm = fminf(pm, __shfl_down(pm, o));
            px = fmaxf(px, __shfl_down(px, o));
        }
        if (tid == 0) {
            const float mnf = pm, mxf = px;
            const float b0 = beta[0], b1 = beta[1], b2 = beta[2];
            const float bm = fmaxf(b0, fmaxf(b1, b2));
            const float e0 = expf(b0 - bm), e1 = expf(b1 - bm),
                        e2 = expf(b2 - bm);
            const float inv = 1.0f / (e0 + e1 + e2);
            const float range = mxf - mnf;
            cns[0] = mnf;
            cns[1] = range / 3.0f;
            cns[2] = range / 15.0f;
            cns[3] = range / 255.0f;
            cns[4] = e0 * inv;
            cns[5] = e1 * inv;
            cns[6] = e2 * inv;
            // returned scale = final loop iteration's (bit=8)
            if (blockIdx.x == 0) out[NTOT] = range / 255.0f;
        }
    }
    __syncthreads();
    const float mnf = cns[0], sc2 = cns[1], sc4 = cns[2], sc8 = cns[3];
    const float sw0 = cns[4], sw1 = cns[5], sw2 = cns[6];

    const int plane = blockIdx.x;          // 0..8191
    const int c = plane & (C_ - 1);        // channel of this plane
    bool f = false;
    #pragma unroll
    for (int j = 0; j < NSEL; ++j) f = f || (sel[j] == c);  // uniform scalar

    const f32x4* __restrict__ src =
        reinterpret_cast<const f32x4*>(in) + (size_t)plane * HW4;
    f32x4* __restrict__ dst =
        reinterpret_cast<f32x4*>(out) + (size_t)plane * HW4;

    // batch 4 independent loads (784 = 3*256 + 16; tail load clamped so
    // every lane loads valid data, only tid<16 stores it)
    f32x4 v0 = src[tid];
    f32x4 v1 = src[tid + 256];
    f32x4 v2 = src[tid + 512];
    f32x4 v3 = src[(tid < 16) ? (tid + 768) : (HW4 - 1)];

    if (f) {  // block-uniform branch
        qmix4(v0, mnf, sc2, sc4, sc8, sw0, sw1, sw2);
        qmix4(v1, mnf, sc2, sc4, sc8, sw0, sw1, sw2);
        qmix4(v2, mnf, sc2, sc4, sc8, sw0, sw1, sw2);
        qmix4(v3, mnf, sc2, sc4, sc8, sw0, sw1, sw2);
    }

    dst[tid]       = v0;
    dst[tid + 256] = v1;
    dst[tid + 512] = v2;
    if (tid < 16) dst[tid + 768] = v3;
}

extern "C" void kernel_launch(void* const* d_in, const int* in_sizes, int n_in,
                              void* d_out, int out_size, void* d_ws, size_t ws_size,
                              hipStream_t stream) {
    const float* input = (const float*)d_in[0];
    const float* beta  = (const float*)d_in[1];
    const int*   sel   = (const int*)d_in[2];
    float* out = (float*)d_out;
    float* ws  = (float*)d_ws;

    // 1) partial min/max over the selected slice (64 partial pairs)
    k_minmax<<<RB, TPB, 0, stream>>>(input, sel, ws);
    // 2) per-plane finish + batched copy / quant-mix
    k_main3<<<PLANES, TPB, 0, stream>>>(input, beta, sel, out, ws);
}